// Round 9
// baseline (305.954 us; speedup 1.0000x reference)
//
#include <hip/hip_runtime.h>
#include <hip/hip_fp16.h>

typedef _Float16 half8 __attribute__((ext_vector_type(8)));
typedef float float4v __attribute__((ext_vector_type(4)));

#define CHUNK 2048           // edges per hist/scatter block
#define BCAP  6144           // LDS staging capacity in k_bucket (avg bucket ~4096)

// ========== phase 1: per-chunk LDS histogram over buckets (dst>>8) ==========
__global__ void k_hist(const int* __restrict__ dst, int E, int* __restrict__ hist, int K) {
    __shared__ int lh[256];
    int t = threadIdx.x, b = blockIdx.x;
    lh[t] = 0;
    __syncthreads();
    int base = b * CHUNK;
    #pragma unroll
    for (int i = 0; i < 8; ++i) {
        int e = base + i * 256 + t;
        if (e < E) atomicAdd(&lh[dst[e] >> 8], 1);   // LDS atomic
    }
    __syncthreads();
    if (t < K) hist[b * K + t] = lh[t];
}

// ========== phase 2: single-block scan of hist + wfc + pool-zero ==========
__global__ void k_scan(int* __restrict__ hist, int NB, int K, int E,
                       int* __restrict__ bucketBase, int* __restrict__ bucketCnt,
                       const float* __restrict__ W3, const float* __restrict__ fcW,
                       const float* __restrict__ b3, float* __restrict__ wfc,
                       double* __restrict__ pool, int* __restrict__ rowptr, int N) {
    __shared__ int tot[256], sc[256];
    int t = threadIdx.x;
    pool[t] = 0.0;
    if (t == 0) rowptr[N] = E;
    if (t < 64) {                       // wfc[c] = (W3@fcW)[c]; wfc[64] = b3.fcW
        float v = 0.f;
        #pragma unroll 8
        for (int j = 0; j < 64; ++j) v += W3[t * 64 + j] * fcW[j];
        wfc[t] = v;
        float bb = b3[t] * fcW[t];
        for (int o = 32; o > 0; o >>= 1) bb += __shfl_down(bb, o, 64);
        if (t == 0) wfc[64] = bb;
    }
    int s = 0;
    if (t < K) for (int b = 0; b < NB; ++b) s += hist[b * K + t];
    tot[t] = (t < K) ? s : 0;
    sc[t] = tot[t];
    __syncthreads();
    for (int o = 1; o < 256; o <<= 1) {
        int v = (t >= o) ? sc[t - o] : 0;
        __syncthreads();
        sc[t] += v;
        __syncthreads();
    }
    int base = sc[t] - tot[t];          // exclusive
    if (t < K) {
        bucketBase[t] = base;
        bucketCnt[t] = s;
        int run = base;                 // rewrite hist in place -> per-(chunk,bucket) offsets
        for (int b = 0; b < NB; ++b) {
            int tmp = hist[b * K + t];
            hist[b * K + t] = run;
            run += tmp;
        }
    }
}

// ========== phase 3: scatter edges into bucket-partitioned pairs ==========
__global__ void k_scatter(const int* __restrict__ src, const int* __restrict__ dst, int E,
                          const int* __restrict__ hist, int K, unsigned* __restrict__ pairs) {
    __shared__ int cur[256];
    int t = threadIdx.x, b = blockIdx.x;
    if (t < K) cur[t] = hist[b * K + t];
    __syncthreads();
    int base = b * CHUNK;
    #pragma unroll
    for (int i = 0; i < 8; ++i) {
        int e = base + i * 256 + t;
        if (e < E) {
            int d = dst[e];
            int pos = atomicAdd(&cur[d >> 8], 1);    // LDS atomic
            pairs[pos] = ((unsigned)(d & 255) << 16) | (unsigned)src[e];
        }
    }
}

// ========== phase 4: per-bucket exact CSR + rowptr/dinv/gx (all LDS-local) ==========
__global__ void k_bucket(const unsigned* __restrict__ pairs, const int* __restrict__ bucketBase,
                         const int* __restrict__ bucketCnt, const float* __restrict__ x,
                         int* __restrict__ rowptr, float* __restrict__ dinv,
                         __half* __restrict__ gx, unsigned short* __restrict__ col, int N) {
    __shared__ unsigned pl[BCAP];
    __shared__ int h[256], nb[256], cur[256];
    int k = blockIdx.x, t = threadIdx.x;
    int base = bucketBase[k], cnt = bucketCnt[k];
    bool stg = cnt <= BCAP;
    h[t] = 0;
    if (stg) for (int i = t; i < cnt; i += 256) pl[i] = pairs[base + i];
    __syncthreads();
    for (int i = t; i < cnt; i += 256) {
        unsigned p = stg ? pl[i] : pairs[base + i];
        atomicAdd(&h[p >> 16], 1);                   // LDS atomic
    }
    __syncthreads();
    int d = h[t];
    nb[t] = d;
    __syncthreads();
    for (int o = 1; o < 256; o <<= 1) {
        int v = (t >= o) ? nb[t - o] : 0;
        __syncthreads();
        nb[t] += v;
        __syncthreads();
    }
    int excl = nb[t] - d;
    cur[t] = excl;
    int gid = (k << 8) + t;
    if (gid < N) {
        rowptr[gid] = base + excl;
        float di = rsqrtf((float)(d + 1));           // +1 self loop
        dinv[gid] = di;
        #pragma unroll
        for (int q = 0; q < 16; ++q)
            gx[gid * 16 + q] = __float2half(q < 10 ? x[gid * 10 + q] * di : 0.f);
    }
    __syncthreads();
    for (int i = t; i < cnt; i += 256) {
        unsigned p = stg ? pl[i] : pairs[base + i];
        int j = p >> 16;
        int pos = atomicAdd(&cur[j], 1);             // LDS atomic
        col[base + pos] = (unsigned short)(p & 0xFFFFu);
    }
}

// ========== layer 1: gather gx16 (1.6MB, L2-resident), 16 lanes/node ==========
__global__ void k_L1(const __half* __restrict__ gx, const float* __restrict__ W1,
                     const float* __restrict__ b1, const int* __restrict__ rowptr,
                     const unsigned short* __restrict__ col, const float* __restrict__ dinv,
                     __half* __restrict__ g1a, __half* __restrict__ g1b, int N) {
    __shared__ float sW[10 * 64];
    __shared__ float sB[64];
    int t = threadIdx.x;
    for (int i = t; i < 640; i += 256) sW[i] = W1[i];
    if (t < 64) sB[t] = b1[t];
    __syncthreads();
    int node = blockIdx.x * 16 + (t >> 4);
    int f = t & 15;
    bool live = node < N;
    bool act = live && (f < 10);
    const char* gp = (const char*)gx;
    unsigned fo = (unsigned)(f << 1);
    float di = live ? dinv[node] : 0.f;
    float a = act ? __half2float(*(const __half*)(gp + ((unsigned)node << 5) + fo)) : 0.f;
    int s0 = 0, s1 = 0;
    if (live) { s0 = rowptr[node]; s1 = rowptr[node + 1]; }
    int e = s0;
    for (; e + 4 <= s1; e += 4) {
        unsigned j0 = col[e], j1 = col[e + 1], j2 = col[e + 2], j3 = col[e + 3];
        float v0 = 0.f, v1 = 0.f, v2 = 0.f, v3 = 0.f;
        if (act) {
            v0 = __half2float(*(const __half*)(gp + (j0 << 5) + fo));
            v1 = __half2float(*(const __half*)(gp + (j1 << 5) + fo));
            v2 = __half2float(*(const __half*)(gp + (j2 << 5) + fo));
            v3 = __half2float(*(const __half*)(gp + (j3 << 5) + fo));
        }
        a += (v0 + v1) + (v2 + v3);
    }
    for (; e < s1; ++e) {
        unsigned j = col[e];
        if (act) a += __half2float(*(const __half*)(gp + (j << 5) + fo));
    }
    a *= di;                                   // P_i(x)[f], f<10
    int gb = t & 48;
    float c0 = 0.f, c1 = 0.f, c2 = 0.f, c3 = 0.f;
    int c4 = 4 * f;
    #pragma unroll
    for (int k = 0; k < 10; ++k) {
        float ak = __shfl(a, gb + k, 64);
        c0 += ak * sW[k * 64 + c4];
        c1 += ak * sW[k * 64 + c4 + 1];
        c2 += ak * sW[k * 64 + c4 + 2];
        c3 += ak * sW[k * 64 + c4 + 3];
    }
    if (!live) return;
    float h0 = di * fmaxf(c0 + sB[c4], 0.f);
    float h1 = di * fmaxf(c1 + sB[c4 + 1], 0.f);
    float h2 = di * fmaxf(c2 + sB[c4 + 2], 0.f);
    float h3 = di * fmaxf(c3 + sB[c4 + 3], 0.f);
    union { __half h[4]; uint2 u; } pk;
    pk.h[0] = __float2half(h0); pk.h[1] = __float2half(h1);
    pk.h[2] = __float2half(h2); pk.h[3] = __float2half(h3);
    if (f < 8)
        *(uint2*)((char*)g1a + ((unsigned)node << 6) + (unsigned)(f << 3)) = pk.u;
    else
        *(uint2*)((char*)g1b + ((unsigned)node << 6) + (unsigned)((f - 8) << 3)) = pk.u;
}

// ========== layer 2 pass A: gather g1a (3.2MB, L2-resident) -> a2a fp16 ==========
__global__ void __launch_bounds__(256) k_L2a(
        const __half* __restrict__ g1a, const int* __restrict__ rowptr,
        const unsigned short* __restrict__ col, const float* __restrict__ dinv,
        __half* __restrict__ a2a, int N) {
    int t = threadIdx.x;
    int node = blockIdx.x * 16 + (t >> 4);
    int f4 = t & 15;
    if (node >= N) return;
    float di = dinv[node];
    const char* gp = (const char*)g1a;
    unsigned fo = (unsigned)(f4 << 2);
    unsigned u = *(const unsigned*)(gp + ((unsigned)node << 6) + fo);
    float2 a = __half22float2(*(__half2*)&u);
    int s0 = rowptr[node], s1 = rowptr[node + 1];
    int e = s0;
    for (; e + 8 <= s1; e += 8) {
        unsigned j0 = col[e],     j1 = col[e + 1], j2 = col[e + 2], j3 = col[e + 3];
        unsigned j4 = col[e + 4], j5 = col[e + 5], j6 = col[e + 6], j7 = col[e + 7];
        unsigned u0 = *(const unsigned*)(gp + (j0 << 6) + fo);
        unsigned u1 = *(const unsigned*)(gp + (j1 << 6) + fo);
        unsigned u2 = *(const unsigned*)(gp + (j2 << 6) + fo);
        unsigned u3 = *(const unsigned*)(gp + (j3 << 6) + fo);
        unsigned u4 = *(const unsigned*)(gp + (j4 << 6) + fo);
        unsigned u5 = *(const unsigned*)(gp + (j5 << 6) + fo);
        unsigned u6 = *(const unsigned*)(gp + (j6 << 6) + fo);
        unsigned u7 = *(const unsigned*)(gp + (j7 << 6) + fo);
        float2 f0 = __half22float2(*(__half2*)&u0), f1 = __half22float2(*(__half2*)&u1);
        float2 f2 = __half22float2(*(__half2*)&u2), f3 = __half22float2(*(__half2*)&u3);
        float2 f4v = __half22float2(*(__half2*)&u4), f5 = __half22float2(*(__half2*)&u5);
        float2 f6 = __half22float2(*(__half2*)&u6), f7 = __half22float2(*(__half2*)&u7);
        a.x += ((f0.x + f1.x) + (f2.x + f3.x)) + ((f4v.x + f5.x) + (f6.x + f7.x));
        a.y += ((f0.y + f1.y) + (f2.y + f3.y)) + ((f4v.y + f5.y) + (f6.y + f7.y));
    }
    for (; e < s1; ++e) {
        unsigned u1 = *(const unsigned*)(gp + ((unsigned)col[e] << 6) + fo);
        float2 f1 = __half22float2(*(__half2*)&u1);
        a.x += f1.x; a.y += f1.y;
    }
    __half2 hv = __floats2half2_rn(a.x * di, a.y * di);
    __builtin_nontemporal_store(*(unsigned*)&hv,
        (unsigned*)((char*)a2a + ((unsigned)node << 6) + fo));
}

// ========== layer 2 pass B: gather g1b + merge a2a + MFMA epilogue -> tvec ==========
__global__ void __launch_bounds__(256) k_L2b(
        const __half* __restrict__ g1b, const __half* __restrict__ a2a,
        const float* __restrict__ W2, const float* __restrict__ b2,
        const float* __restrict__ wfcv, const int* __restrict__ rowptr,
        const unsigned short* __restrict__ col, const float* __restrict__ dinv,
        float* __restrict__ tvec, int N) {
    __shared__ __half At[16 * 72];     // 16 nodes x 64 feats, stride 72
    __shared__ float sRed[4][16];
    __shared__ float sDi[16];
    int t = threadIdx.x;
    int lane = t & 63, wid = t >> 6;
    int m = lane & 15, quad = lane >> 4;

    // B fragments: W2 column cg, fp16 hi/lo split (registers, overlaps gather)
    int cg = (wid << 4) + m;
    half8 H0, L0, H1, L1;
    #pragma unroll
    for (int j = 0; j < 8; ++j) {
        float w0 = W2[(quad * 8 + j) * 64 + cg];
        _Float16 h0 = (_Float16)w0;
        H0[j] = h0; L0[j] = (_Float16)(w0 - (float)h0);
        float w1 = W2[(32 + quad * 8 + j) * 64 + cg];
        _Float16 h1 = (_Float16)w1;
        H1[j] = h1; L1[j] = (_Float16)(w1 - (float)h1);
    }
    float bc = b2[cg], wf = wfcv[cg];

    // gather g1b: 16 nodes/block, 16 lanes/node, 2 feats (uint) per lane
    int nl = t >> 4, f4 = t & 15;
    int node = blockIdx.x * 16 + nl;
    bool live = node < N;
    float di = live ? dinv[node] : 0.f;
    float ax = 0.f, ay = 0.f;
    unsigned ua = 0u;
    if (live) {
        const char* gp = (const char*)g1b;
        unsigned fo = (unsigned)(f4 << 2);
        unsigned u = *(const unsigned*)(gp + ((unsigned)node << 6) + fo);
        float2 fs = __half22float2(*(__half2*)&u);
        ax = fs.x; ay = fs.y;
        int s0 = rowptr[node], s1 = rowptr[node + 1];
        int e = s0;
        for (; e + 8 <= s1; e += 8) {
            unsigned j0 = col[e],     j1 = col[e + 1], j2 = col[e + 2], j3 = col[e + 3];
            unsigned j4 = col[e + 4], j5 = col[e + 5], j6 = col[e + 6], j7 = col[e + 7];
            unsigned u0 = *(const unsigned*)(gp + (j0 << 6) + fo);
            unsigned u1 = *(const unsigned*)(gp + (j1 << 6) + fo);
            unsigned u2 = *(const unsigned*)(gp + (j2 << 6) + fo);
            unsigned u3 = *(const unsigned*)(gp + (j3 << 6) + fo);
            unsigned u4 = *(const unsigned*)(gp + (j4 << 6) + fo);
            unsigned u5 = *(const unsigned*)(gp + (j5 << 6) + fo);
            unsigned u6 = *(const unsigned*)(gp + (j6 << 6) + fo);
            unsigned u7 = *(const unsigned*)(gp + (j7 << 6) + fo);
            float2 f0 = __half22float2(*(__half2*)&u0), f1 = __half22float2(*(__half2*)&u1);
            float2 f2 = __half22float2(*(__half2*)&u2), f3 = __half22float2(*(__half2*)&u3);
            float2 f4v = __half22float2(*(__half2*)&u4), f5 = __half22float2(*(__half2*)&u5);
            float2 f6 = __half22float2(*(__half2*)&u6), f7 = __half22float2(*(__half2*)&u7);
            ax += ((f0.x + f1.x) + (f2.x + f3.x)) + ((f4v.x + f5.x) + (f6.x + f7.x));
            ay += ((f0.y + f1.y) + (f2.y + f3.y)) + ((f4v.y + f5.y) + (f6.y + f7.y));
        }
        for (; e < s1; ++e) {
            unsigned u1 = *(const unsigned*)(gp + ((unsigned)col[e] << 6) + fo);
            float2 f1 = __half22float2(*(__half2*)&u1);
            ax += f1.x; ay += f1.y;
        }
        ua = __builtin_nontemporal_load(
            (const unsigned*)((const char*)a2a + ((unsigned)node << 6) + fo));
    }
    __half2 hv = __floats2half2_rn(ax * di, ay * di);
    *(unsigned*)&At[nl * 72 + 32 + 2 * f4] = *(unsigned*)&hv;   // b-half
    *(unsigned*)&At[nl * 72 + 2 * f4] = ua;                     // a-half (from pass A)
    if (f4 == 0) sDi[nl] = di;
    __syncthreads();

    // MFMA: D[m=node][n=col] = A(16x64) @ W2(64x64); this wave: cols 16*wid..
    half8 A0 = *reinterpret_cast<const half8*>(&At[m * 72 + quad * 8]);
    half8 A1 = *reinterpret_cast<const half8*>(&At[m * 72 + 32 + quad * 8]);
    float4v C = {0.f, 0.f, 0.f, 0.f};
    C = __builtin_amdgcn_mfma_f32_16x16x32_f16(A0, H0, C, 0, 0, 0);
    C = __builtin_amdgcn_mfma_f32_16x16x32_f16(A0, L0, C, 0, 0, 0);
    C = __builtin_amdgcn_mfma_f32_16x16x32_f16(A1, H1, C, 0, 0, 0);
    C = __builtin_amdgcn_mfma_f32_16x16x32_f16(A1, L1, C, 0, 0, 0);

    // epilogue: relu(C+b2)*wfc, reduce over cols -> per-node scalar
    float v0 = fmaxf(C[0] + bc, 0.f) * wf;
    float v1 = fmaxf(C[1] + bc, 0.f) * wf;
    float v2 = fmaxf(C[2] + bc, 0.f) * wf;
    float v3 = fmaxf(C[3] + bc, 0.f) * wf;
    #pragma unroll
    for (int o = 1; o < 16; o <<= 1) {
        v0 += __shfl_xor(v0, o, 64);
        v1 += __shfl_xor(v1, o, 64);
        v2 += __shfl_xor(v2, o, 64);
        v3 += __shfl_xor(v3, o, 64);
    }
    if (m == 0) {
        sRed[wid][quad * 4 + 0] = v0;
        sRed[wid][quad * 4 + 1] = v1;
        sRed[wid][quad * 4 + 2] = v2;
        sRed[wid][quad * 4 + 3] = v3;
    }
    __syncthreads();
    if (t < 16) {
        int ng = blockIdx.x * 16 + t;
        if (ng < N) {
            float tt = sRed[0][t] + sRed[1][t] + sRed[2][t] + sRed[3][t];
            tvec[ng] = sDi[t] * tt;            // t_j = dinv_j * (h2_j . wfc)
        }
    }
}

// ========== layer 3: scalar gather over tvec (200KB) + mean-pool ==========
__global__ void k_agg3(const float* __restrict__ tvec, const int* __restrict__ rowptr,
                       const unsigned short* __restrict__ col, const float* __restrict__ dinv,
                       double* __restrict__ pool, int N) {
    int tid = blockIdx.x * 256 + threadIdx.x;
    int node = tid >> 4, lane = tid & 15;
    if (node >= N) return;
    int s0 = rowptr[node], s1 = rowptr[node + 1];
    float s = 0.f;
    for (int e = s0 + lane; e < s1; e += 16) s += tvec[col[e]];
    #pragma unroll
    for (int o = 1; o < 16; o <<= 1) s += __shfl_xor(s, o, 64);
    if (lane == 0) {
        double contrib = (double)(dinv[node] * (tvec[node] + s));
        atomicAdd(&pool[node & 255], contrib);
    }
}

__global__ void k_final(const double* __restrict__ pool, const float* __restrict__ wfc,
                        const float* __restrict__ fcb, float* __restrict__ out, double invN) {
    __shared__ double s[256];
    int t = threadIdx.x;
    s[t] = pool[t];
    __syncthreads();
    for (int o = 128; o > 0; o >>= 1) {
        if (t < o) s[t] += s[t + o];
        __syncthreads();
    }
    if (t == 0) out[0] = (float)(s[0] * invN) + wfc[64] + fcb[0];
}

extern "C" void kernel_launch(void* const* d_in, const int* in_sizes, int n_in,
                              void* d_out, int out_size, void* d_ws, size_t ws_size,
                              hipStream_t stream) {
    const float* x   = (const float*)d_in[0];
    const int*   ei  = (const int*)d_in[1];
    const float* W1  = (const float*)d_in[2];
    const float* b1  = (const float*)d_in[3];
    const float* W2  = (const float*)d_in[4];
    const float* b2  = (const float*)d_in[5];
    const float* W3  = (const float*)d_in[6];
    const float* b3  = (const float*)d_in[7];
    const float* fcW = (const float*)d_in[8];
    const float* fcb = (const float*)d_in[9];

    const int N = in_sizes[0] / 10;
    const int E = in_sizes[1] / 2;
    const int* src = ei;
    const int* dst = ei + E;

    const int K  = (N + 255) >> 8;            // buckets of 256 nodes (196 for N=50000)
    const int NB = (E + CHUNK - 1) / CHUNK;   // hist/scatter chunks (391)

    // ---- workspace carve-up (256B aligned) ----
    char* w = (char*)d_ws;
    size_t off = 0;
    auto alloc = [&](size_t bytes) -> void* {
        void* p = w + off;
        off += (bytes + 255) & ~(size_t)255;
        return p;
    };
    int*      hist       = (int*)alloc((size_t)NB * K * 4);
    int*      bucketBase = (int*)alloc((size_t)K * 4);
    int*      bucketCnt  = (int*)alloc((size_t)K * 4);
    unsigned* pairs      = (unsigned*)alloc((size_t)E * 4);
    unsigned short* col  = (unsigned short*)alloc((size_t)E * 2);
    int*      rowptr     = (int*)alloc((size_t)(N + 1) * 4);
    float*    dinv       = (float*)alloc((size_t)N * 4);
    double*   pool       = (double*)alloc(256 * 8);
    float*    wfc        = (float*)alloc(65 * 4);
    float*    tvec       = (float*)alloc((size_t)N * 4);
    __half*   gx         = (__half*)alloc((size_t)N * 16 * 2);
    __half*   g1a        = (__half*)alloc((size_t)N * 32 * 2);
    __half*   g1b        = (__half*)alloc((size_t)N * 32 * 2);
    __half*   a2a        = (__half*)alloc((size_t)N * 32 * 2);
    (void)ws_size; (void)n_in; (void)out_size;

    const int nbNode16 = (N + 15) / 16;

    // ---- atomic-free CSR build (counting sort, LDS atomics only) ----
    k_hist   <<<NB, 256, 0, stream>>>(dst, E, hist, K);
    k_scan   <<<1, 256, 0, stream>>>(hist, NB, K, E, bucketBase, bucketCnt,
                                     W3, fcW, b3, wfc, pool, rowptr, N);
    k_scatter<<<NB, 256, 0, stream>>>(src, dst, E, hist, K, pairs);
    k_bucket <<<K, 256, 0, stream>>>(pairs, bucketBase, bucketCnt, x,
                                     rowptr, dinv, gx, col, N);

    // ---- fused layers ----
    k_L1 <<<nbNode16, 256, 0, stream>>>(gx, W1, b1, rowptr, col, dinv, g1a, g1b, N);
    k_L2a<<<nbNode16, 256, 0, stream>>>(g1a, rowptr, col, dinv, a2a, N);
    k_L2b<<<nbNode16, 256, 0, stream>>>(g1b, a2a, W2, b2, wfc, rowptr, col, dinv, tvec, N);
    k_agg3<<<nbNode16, 256, 0, stream>>>(tvec, rowptr, col, dinv, pool, N);
    k_final<<<1, 256, 0, stream>>>(pool, wfc, fcb, (float*)d_out, 1.0 / (double)N);
}

// Round 10
// 168.794 us; speedup vs baseline: 1.8126x; 1.8126x over previous
//
#include <hip/hip_runtime.h>
#include <hip/hip_fp16.h>

typedef _Float16 half8 __attribute__((ext_vector_type(8)));
typedef float float4v __attribute__((ext_vector_type(4)));

#define CHUNK 2048           // edges per hist/scatter block
#define BCAP  6144           // LDS staging capacity in k_bucket

// ========== phase 1: per-chunk LDS histogram, transposed store ==========
__global__ void k_hist(const int* __restrict__ dst, int E, int* __restrict__ histT,
                       int K, int NBS) {
    __shared__ int lh[256];
    int t = threadIdx.x, b = blockIdx.x;
    lh[t] = 0;
    __syncthreads();
    int base = b * CHUNK;
    #pragma unroll
    for (int i = 0; i < 8; ++i) {
        int e = base + i * 256 + t;
        if (e < E) atomicAdd(&lh[dst[e] >> 8], 1);   // LDS atomic
    }
    __syncthreads();
    if (t < K) histT[t * NBS + b] = lh[t];
}

// ========== phase 2a: per-bucket totals (one wave per bucket) ==========
__global__ void k_tot(const int* __restrict__ histT, int NB, int NBS, int* __restrict__ tot) {
    int k = blockIdx.x, t = threadIdx.x;
    int s = 0;
    for (int b = t; b < NB; b += 64) s += histT[k * NBS + b];
    for (int o = 32; o > 0; o >>= 1) s += __shfl_down(s, o, 64);
    if (t == 0) tot[k] = s;
}

// ========== phase 2b: scan over K totals + wfc + pool-zero (tiny) ==========
__global__ void k_scanK(const int* __restrict__ tot, int K, int E,
                        int* __restrict__ bucketBase, int* __restrict__ bucketCnt,
                        const float* __restrict__ W3, const float* __restrict__ fcW,
                        const float* __restrict__ b3, float* __restrict__ wfc,
                        double* __restrict__ pool, int* __restrict__ rowptr, int N) {
    __shared__ int sc[256];
    int t = threadIdx.x;
    pool[t] = 0.0;
    if (t == 0) rowptr[N] = E;
    if (t < 64) {                       // wfc[c] = (W3@fcW)[c]; wfc[64] = b3.fcW
        float v = 0.f;
        #pragma unroll 8
        for (int j = 0; j < 64; ++j) v += W3[t * 64 + j] * fcW[j];
        wfc[t] = v;
        float bb = b3[t] * fcW[t];
        for (int o = 32; o > 0; o >>= 1) bb += __shfl_down(bb, o, 64);
        if (t == 0) wfc[64] = bb;
    }
    int v = (t < K) ? tot[t] : 0;
    sc[t] = v;
    __syncthreads();
    for (int o = 1; o < 256; o <<= 1) {
        int u = (t >= o) ? sc[t - o] : 0;
        __syncthreads();
        sc[t] += u;
        __syncthreads();
    }
    if (t < K) {
        bucketBase[t] = sc[t] - v;
        bucketCnt[t] = v;
    }
}

// ========== phase 2c: per-bucket chunk-offset scan (K blocks, tiled w/ carry) ==========
__global__ void k_offsets(int* __restrict__ histT, int NB, int NBS,
                          const int* __restrict__ bucketBase) {
    __shared__ int sc[256];
    int k = blockIdx.x, t = threadIdx.x;
    int carry = bucketBase[k];
    for (int tile = 0; tile < NB; tile += 256) {
        int b = tile + t;
        int v = (b < NB) ? histT[k * NBS + b] : 0;
        sc[t] = v;
        __syncthreads();
        for (int o = 1; o < 256; o <<= 1) {
            int u = (t >= o) ? sc[t - o] : 0;
            __syncthreads();
            sc[t] += u;
            __syncthreads();
        }
        if (b < NB) histT[k * NBS + b] = carry + sc[t] - v;
        int tileSum = sc[255];
        __syncthreads();
        carry += tileSum;
    }
}

// ========== phase 3: scatter edges into bucket-partitioned pairs ==========
__global__ void k_scatter(const int* __restrict__ src, const int* __restrict__ dst, int E,
                          const int* __restrict__ histT, int K, int NBS,
                          unsigned* __restrict__ pairs) {
    __shared__ int cur[256];
    int t = threadIdx.x, b = blockIdx.x;
    if (t < K) cur[t] = histT[t * NBS + b];
    __syncthreads();
    int base = b * CHUNK;
    #pragma unroll
    for (int i = 0; i < 8; ++i) {
        int e = base + i * 256 + t;
        if (e < E) {
            int d = dst[e];
            int pos = atomicAdd(&cur[d >> 8], 1);    // LDS atomic
            pairs[pos] = ((unsigned)(d & 255) << 16) | (unsigned)src[e];
        }
    }
}

// ========== phase 4: per-bucket exact CSR + rowptr/dinv/gx (all LDS-local) ==========
__global__ void k_bucket(const unsigned* __restrict__ pairs, const int* __restrict__ bucketBase,
                         const int* __restrict__ bucketCnt, const float* __restrict__ x,
                         int* __restrict__ rowptr, float* __restrict__ dinv,
                         __half* __restrict__ gx, unsigned short* __restrict__ col, int N) {
    __shared__ unsigned pl[BCAP];
    __shared__ int h[256], nb[256], cur[256];
    int k = blockIdx.x, t = threadIdx.x;
    int base = bucketBase[k], cnt = bucketCnt[k];
    bool stg = cnt <= BCAP;
    h[t] = 0;
    if (stg) for (int i = t; i < cnt; i += 256) pl[i] = pairs[base + i];
    __syncthreads();
    for (int i = t; i < cnt; i += 256) {
        unsigned p = stg ? pl[i] : pairs[base + i];
        atomicAdd(&h[p >> 16], 1);                   // LDS atomic
    }
    __syncthreads();
    int d = h[t];
    nb[t] = d;
    __syncthreads();
    for (int o = 1; o < 256; o <<= 1) {
        int v = (t >= o) ? nb[t - o] : 0;
        __syncthreads();
        nb[t] += v;
        __syncthreads();
    }
    int excl = nb[t] - d;
    cur[t] = excl;
    int gid = (k << 8) + t;
    if (gid < N) {
        rowptr[gid] = base + excl;
        float di = rsqrtf((float)(d + 1));           // +1 self loop
        dinv[gid] = di;
        #pragma unroll
        for (int q = 0; q < 16; ++q)
            gx[gid * 16 + q] = __float2half(q < 10 ? x[gid * 10 + q] * di : 0.f);
    }
    __syncthreads();
    for (int i = t; i < cnt; i += 256) {
        unsigned p = stg ? pl[i] : pairs[base + i];
        int j = p >> 16;
        int pos = atomicAdd(&cur[j], 1);             // LDS atomic
        col[base + pos] = (unsigned short)(p & 0xFFFFu);
    }
}

// ========== layer 1: gather gx16 (1.6MB, L2-resident), 16 lanes/node ==========
__global__ void k_L1(const __half* __restrict__ gx, const float* __restrict__ W1,
                     const float* __restrict__ b1, const int* __restrict__ rowptr,
                     const unsigned short* __restrict__ col, const float* __restrict__ dinv,
                     __half* __restrict__ g1a, __half* __restrict__ g1b, int N) {
    __shared__ float sW[10 * 64];
    __shared__ float sB[64];
    int t = threadIdx.x;
    for (int i = t; i < 640; i += 256) sW[i] = W1[i];
    if (t < 64) sB[t] = b1[t];
    __syncthreads();
    int node = blockIdx.x * 16 + (t >> 4);
    int f = t & 15;
    bool live = node < N;
    bool act = live && (f < 10);
    const char* gp = (const char*)gx;
    unsigned fo = (unsigned)(f << 1);
    float di = live ? dinv[node] : 0.f;
    float a = act ? __half2float(*(const __half*)(gp + ((unsigned)node << 5) + fo)) : 0.f;
    int s0 = 0, s1 = 0;
    if (live) { s0 = rowptr[node]; s1 = rowptr[node + 1]; }
    int e = s0;
    for (; e + 4 <= s1; e += 4) {
        unsigned j0 = col[e], j1 = col[e + 1], j2 = col[e + 2], j3 = col[e + 3];
        float v0 = 0.f, v1 = 0.f, v2 = 0.f, v3 = 0.f;
        if (act) {
            v0 = __half2float(*(const __half*)(gp + (j0 << 5) + fo));
            v1 = __half2float(*(const __half*)(gp + (j1 << 5) + fo));
            v2 = __half2float(*(const __half*)(gp + (j2 << 5) + fo));
            v3 = __half2float(*(const __half*)(gp + (j3 << 5) + fo));
        }
        a += (v0 + v1) + (v2 + v3);
    }
    for (; e < s1; ++e) {
        unsigned j = col[e];
        if (act) a += __half2float(*(const __half*)(gp + (j << 5) + fo));
    }
    a *= di;                                   // P_i(x)[f], f<10
    int gb = t & 48;
    float c0 = 0.f, c1 = 0.f, c2 = 0.f, c3 = 0.f;
    int c4 = 4 * f;
    #pragma unroll
    for (int k = 0; k < 10; ++k) {
        float ak = __shfl(a, gb + k, 64);
        c0 += ak * sW[k * 64 + c4];
        c1 += ak * sW[k * 64 + c4 + 1];
        c2 += ak * sW[k * 64 + c4 + 2];
        c3 += ak * sW[k * 64 + c4 + 3];
    }
    if (!live) return;
    float h0 = di * fmaxf(c0 + sB[c4], 0.f);
    float h1 = di * fmaxf(c1 + sB[c4 + 1], 0.f);
    float h2 = di * fmaxf(c2 + sB[c4 + 2], 0.f);
    float h3 = di * fmaxf(c3 + sB[c4 + 3], 0.f);
    union { __half h[4]; uint2 u; } pk;
    pk.h[0] = __float2half(h0); pk.h[1] = __float2half(h1);
    pk.h[2] = __float2half(h2); pk.h[3] = __float2half(h3);
    if (f < 8)
        *(uint2*)((char*)g1a + ((unsigned)node << 6) + (unsigned)(f << 3)) = pk.u;
    else
        *(uint2*)((char*)g1b + ((unsigned)node << 6) + (unsigned)((f - 8) << 3)) = pk.u;
}

// ========== layer 2 pass A: gather g1a (3.2MB, L2-resident) -> a2a fp16 ==========
__global__ void __launch_bounds__(256) k_L2a(
        const __half* __restrict__ g1a, const int* __restrict__ rowptr,
        const unsigned short* __restrict__ col, const float* __restrict__ dinv,
        __half* __restrict__ a2a, int N) {
    int t = threadIdx.x;
    int node = blockIdx.x * 16 + (t >> 4);
    int f4 = t & 15;
    if (node >= N) return;
    float di = dinv[node];
    const char* gp = (const char*)g1a;
    unsigned fo = (unsigned)(f4 << 2);
    unsigned u = *(const unsigned*)(gp + ((unsigned)node << 6) + fo);
    float2 a = __half22float2(*(__half2*)&u);
    int s0 = rowptr[node], s1 = rowptr[node + 1];
    int e = s0;
    for (; e + 8 <= s1; e += 8) {
        unsigned j0 = col[e],     j1 = col[e + 1], j2 = col[e + 2], j3 = col[e + 3];
        unsigned j4 = col[e + 4], j5 = col[e + 5], j6 = col[e + 6], j7 = col[e + 7];
        unsigned u0 = *(const unsigned*)(gp + (j0 << 6) + fo);
        unsigned u1 = *(const unsigned*)(gp + (j1 << 6) + fo);
        unsigned u2 = *(const unsigned*)(gp + (j2 << 6) + fo);
        unsigned u3 = *(const unsigned*)(gp + (j3 << 6) + fo);
        unsigned u4 = *(const unsigned*)(gp + (j4 << 6) + fo);
        unsigned u5 = *(const unsigned*)(gp + (j5 << 6) + fo);
        unsigned u6 = *(const unsigned*)(gp + (j6 << 6) + fo);
        unsigned u7 = *(const unsigned*)(gp + (j7 << 6) + fo);
        float2 f0 = __half22float2(*(__half2*)&u0), f1 = __half22float2(*(__half2*)&u1);
        float2 f2 = __half22float2(*(__half2*)&u2), f3 = __half22float2(*(__half2*)&u3);
        float2 f4v = __half22float2(*(__half2*)&u4), f5 = __half22float2(*(__half2*)&u5);
        float2 f6 = __half22float2(*(__half2*)&u6), f7 = __half22float2(*(__half2*)&u7);
        a.x += ((f0.x + f1.x) + (f2.x + f3.x)) + ((f4v.x + f5.x) + (f6.x + f7.x));
        a.y += ((f0.y + f1.y) + (f2.y + f3.y)) + ((f4v.y + f5.y) + (f6.y + f7.y));
    }
    for (; e < s1; ++e) {
        unsigned u1 = *(const unsigned*)(gp + ((unsigned)col[e] << 6) + fo);
        float2 f1 = __half22float2(*(__half2*)&u1);
        a.x += f1.x; a.y += f1.y;
    }
    __half2 hv = __floats2half2_rn(a.x * di, a.y * di);
    __builtin_nontemporal_store(*(unsigned*)&hv,
        (unsigned*)((char*)a2a + ((unsigned)node << 6) + fo));
}

// ========== layer 2 pass B: gather g1b + merge a2a + MFMA epilogue -> tvec ==========
__global__ void __launch_bounds__(256) k_L2b(
        const __half* __restrict__ g1b, const __half* __restrict__ a2a,
        const float* __restrict__ W2, const float* __restrict__ b2,
        const float* __restrict__ wfcv, const int* __restrict__ rowptr,
        const unsigned short* __restrict__ col, const float* __restrict__ dinv,
        float* __restrict__ tvec, int N) {
    __shared__ __half At[16 * 72];     // 16 nodes x 64 feats, stride 72
    __shared__ float sRed[4][16];
    __shared__ float sDi[16];
    int t = threadIdx.x;
    int lane = t & 63, wid = t >> 6;
    int m = lane & 15, quad = lane >> 4;

    // B fragments: W2 column cg, fp16 hi/lo split (registers, overlaps gather)
    int cg = (wid << 4) + m;
    half8 H0, L0, H1, L1;
    #pragma unroll
    for (int j = 0; j < 8; ++j) {
        float w0 = W2[(quad * 8 + j) * 64 + cg];
        _Float16 h0 = (_Float16)w0;
        H0[j] = h0; L0[j] = (_Float16)(w0 - (float)h0);
        float w1 = W2[(32 + quad * 8 + j) * 64 + cg];
        _Float16 h1 = (_Float16)w1;
        H1[j] = h1; L1[j] = (_Float16)(w1 - (float)h1);
    }
    float bc = b2[cg], wf = wfcv[cg];

    // gather g1b: 16 nodes/block, 16 lanes/node, 2 feats (uint) per lane
    int nl = t >> 4, f4 = t & 15;
    int node = blockIdx.x * 16 + nl;
    bool live = node < N;
    float di = live ? dinv[node] : 0.f;
    float ax = 0.f, ay = 0.f;
    unsigned ua = 0u;
    if (live) {
        const char* gp = (const char*)g1b;
        unsigned fo = (unsigned)(f4 << 2);
        unsigned u = *(const unsigned*)(gp + ((unsigned)node << 6) + fo);
        float2 fs = __half22float2(*(__half2*)&u);
        ax = fs.x; ay = fs.y;
        int s0 = rowptr[node], s1 = rowptr[node + 1];
        int e = s0;
        for (; e + 8 <= s1; e += 8) {
            unsigned j0 = col[e],     j1 = col[e + 1], j2 = col[e + 2], j3 = col[e + 3];
            unsigned j4 = col[e + 4], j5 = col[e + 5], j6 = col[e + 6], j7 = col[e + 7];
            unsigned u0 = *(const unsigned*)(gp + (j0 << 6) + fo);
            unsigned u1 = *(const unsigned*)(gp + (j1 << 6) + fo);
            unsigned u2 = *(const unsigned*)(gp + (j2 << 6) + fo);
            unsigned u3 = *(const unsigned*)(gp + (j3 << 6) + fo);
            unsigned u4 = *(const unsigned*)(gp + (j4 << 6) + fo);
            unsigned u5 = *(const unsigned*)(gp + (j5 << 6) + fo);
            unsigned u6 = *(const unsigned*)(gp + (j6 << 6) + fo);
            unsigned u7 = *(const unsigned*)(gp + (j7 << 6) + fo);
            float2 f0 = __half22float2(*(__half2*)&u0), f1 = __half22float2(*(__half2*)&u1);
            float2 f2 = __half22float2(*(__half2*)&u2), f3 = __half22float2(*(__half2*)&u3);
            float2 f4v = __half22float2(*(__half2*)&u4), f5 = __half22float2(*(__half2*)&u5);
            float2 f6 = __half22float2(*(__half2*)&u6), f7 = __half22float2(*(__half2*)&u7);
            ax += ((f0.x + f1.x) + (f2.x + f3.x)) + ((f4v.x + f5.x) + (f6.x + f7.x));
            ay += ((f0.y + f1.y) + (f2.y + f3.y)) + ((f4v.y + f5.y) + (f6.y + f7.y));
        }
        for (; e < s1; ++e) {
            unsigned u1 = *(const unsigned*)(gp + ((unsigned)col[e] << 6) + fo);
            float2 f1 = __half22float2(*(__half2*)&u1);
            ax += f1.x; ay += f1.y;
        }
        ua = __builtin_nontemporal_load(
            (const unsigned*)((const char*)a2a + ((unsigned)node << 6) + fo));
    }
    __half2 hv = __floats2half2_rn(ax * di, ay * di);
    *(unsigned*)&At[nl * 72 + 32 + 2 * f4] = *(unsigned*)&hv;   // b-half
    *(unsigned*)&At[nl * 72 + 2 * f4] = ua;                     // a-half (from pass A)
    if (f4 == 0) sDi[nl] = di;
    __syncthreads();

    // MFMA: D[m=node][n=col] = A(16x64) @ W2(64x64); this wave: cols 16*wid..
    half8 A0 = *reinterpret_cast<const half8*>(&At[m * 72 + quad * 8]);
    half8 A1 = *reinterpret_cast<const half8*>(&At[m * 72 + 32 + quad * 8]);
    float4v C = {0.f, 0.f, 0.f, 0.f};
    C = __builtin_amdgcn_mfma_f32_16x16x32_f16(A0, H0, C, 0, 0, 0);
    C = __builtin_amdgcn_mfma_f32_16x16x32_f16(A0, L0, C, 0, 0, 0);
    C = __builtin_amdgcn_mfma_f32_16x16x32_f16(A1, H1, C, 0, 0, 0);
    C = __builtin_amdgcn_mfma_f32_16x16x32_f16(A1, L1, C, 0, 0, 0);

    // epilogue: relu(C+b2)*wfc, reduce over cols -> per-node scalar
    float v0 = fmaxf(C[0] + bc, 0.f) * wf;
    float v1 = fmaxf(C[1] + bc, 0.f) * wf;
    float v2 = fmaxf(C[2] + bc, 0.f) * wf;
    float v3 = fmaxf(C[3] + bc, 0.f) * wf;
    #pragma unroll
    for (int o = 1; o < 16; o <<= 1) {
        v0 += __shfl_xor(v0, o, 64);
        v1 += __shfl_xor(v1, o, 64);
        v2 += __shfl_xor(v2, o, 64);
        v3 += __shfl_xor(v3, o, 64);
    }
    if (m == 0) {
        sRed[wid][quad * 4 + 0] = v0;
        sRed[wid][quad * 4 + 1] = v1;
        sRed[wid][quad * 4 + 2] = v2;
        sRed[wid][quad * 4 + 3] = v3;
    }
    __syncthreads();
    if (t < 16) {
        int ng = blockIdx.x * 16 + t;
        if (ng < N) {
            float tt = sRed[0][t] + sRed[1][t] + sRed[2][t] + sRed[3][t];
            tvec[ng] = sDi[t] * tt;            // t_j = dinv_j * (h2_j . wfc)
        }
    }
}

// ========== layer 3: scalar gather over tvec (200KB) + mean-pool ==========
__global__ void k_agg3(const float* __restrict__ tvec, const int* __restrict__ rowptr,
                       const unsigned short* __restrict__ col, const float* __restrict__ dinv,
                       double* __restrict__ pool, int N) {
    int tid = blockIdx.x * 256 + threadIdx.x;
    int node = tid >> 4, lane = tid & 15;
    if (node >= N) return;
    int s0 = rowptr[node], s1 = rowptr[node + 1];
    float s = 0.f;
    for (int e = s0 + lane; e < s1; e += 16) s += tvec[col[e]];
    #pragma unroll
    for (int o = 1; o < 16; o <<= 1) s += __shfl_xor(s, o, 64);
    if (lane == 0) {
        double contrib = (double)(dinv[node] * (tvec[node] + s));
        atomicAdd(&pool[node & 255], contrib);
    }
}

__global__ void k_final(const double* __restrict__ pool, const float* __restrict__ wfc,
                        const float* __restrict__ fcb, float* __restrict__ out, double invN) {
    __shared__ double s[256];
    int t = threadIdx.x;
    s[t] = pool[t];
    __syncthreads();
    for (int o = 128; o > 0; o >>= 1) {
        if (t < o) s[t] += s[t + o];
        __syncthreads();
    }
    if (t == 0) out[0] = (float)(s[0] * invN) + wfc[64] + fcb[0];
}

extern "C" void kernel_launch(void* const* d_in, const int* in_sizes, int n_in,
                              void* d_out, int out_size, void* d_ws, size_t ws_size,
                              hipStream_t stream) {
    const float* x   = (const float*)d_in[0];
    const int*   ei  = (const int*)d_in[1];
    const float* W1  = (const float*)d_in[2];
    const float* b1  = (const float*)d_in[3];
    const float* W2  = (const float*)d_in[4];
    const float* b2  = (const float*)d_in[5];
    const float* W3  = (const float*)d_in[6];
    const float* b3  = (const float*)d_in[7];
    const float* fcW = (const float*)d_in[8];
    const float* fcb = (const float*)d_in[9];

    const int N = in_sizes[0] / 10;
    const int E = in_sizes[1] / 2;
    const int* src = ei;
    const int* dst = ei + E;

    const int K   = (N + 255) >> 8;            // buckets of 256 nodes (196)
    const int NB  = (E + CHUNK - 1) / CHUNK;   // chunks (391)
    const int NBS = NB | 1;                    // odd stride

    // ---- workspace carve-up (256B aligned) ----
    char* w = (char*)d_ws;
    size_t off = 0;
    auto alloc = [&](size_t bytes) -> void* {
        void* p = w + off;
        off += (bytes + 255) & ~(size_t)255;
        return p;
    };
    int*      histT      = (int*)alloc((size_t)K * NBS * 4);
    int*      tot        = (int*)alloc((size_t)K * 4);
    int*      bucketBase = (int*)alloc((size_t)K * 4);
    int*      bucketCnt  = (int*)alloc((size_t)K * 4);
    unsigned* pairs      = (unsigned*)alloc((size_t)E * 4);
    unsigned short* col  = (unsigned short*)alloc((size_t)E * 2);
    int*      rowptr     = (int*)alloc((size_t)(N + 1) * 4);
    float*    dinv       = (float*)alloc((size_t)N * 4);
    double*   pool       = (double*)alloc(256 * 8);
    float*    wfc        = (float*)alloc(65 * 4);
    float*    tvec       = (float*)alloc((size_t)N * 4);
    __half*   gx         = (__half*)alloc((size_t)N * 16 * 2);
    __half*   g1a        = (__half*)alloc((size_t)N * 32 * 2);
    __half*   g1b        = (__half*)alloc((size_t)N * 32 * 2);
    __half*   a2a        = (__half*)alloc((size_t)N * 32 * 2);
    (void)ws_size; (void)n_in; (void)out_size;

    const int nbNode16 = (N + 15) / 16;

    // ---- atomic-free CSR build (counting sort, LDS atomics only) ----
    k_hist   <<<NB, 256, 0, stream>>>(dst, E, histT, K, NBS);
    k_tot    <<<K, 64, 0, stream>>>(histT, NB, NBS, tot);
    k_scanK  <<<1, 256, 0, stream>>>(tot, K, E, bucketBase, bucketCnt,
                                     W3, fcW, b3, wfc, pool, rowptr, N);
    k_offsets<<<K, 256, 0, stream>>>(histT, NB, NBS, bucketBase);
    k_scatter<<<NB, 256, 0, stream>>>(src, dst, E, histT, K, NBS, pairs);
    k_bucket <<<K, 256, 0, stream>>>(pairs, bucketBase, bucketCnt, x,
                                     rowptr, dinv, gx, col, N);

    // ---- fused layers ----
    k_L1 <<<nbNode16, 256, 0, stream>>>(gx, W1, b1, rowptr, col, dinv, g1a, g1b, N);
    k_L2a<<<nbNode16, 256, 0, stream>>>(g1a, rowptr, col, dinv, a2a, N);
    k_L2b<<<nbNode16, 256, 0, stream>>>(g1b, a2a, W2, b2, wfc, rowptr, col, dinv, tvec, N);
    k_agg3<<<nbNode16, 256, 0, stream>>>(tvec, rowptr, col, dinv, pool, N);
    k_final<<<1, 256, 0, stream>>>(pool, wfc, fcb, (float*)d_out, 1.0 / (double)N);
}

// Round 11
// 164.104 us; speedup vs baseline: 1.8644x; 1.0286x over previous
//
#include <hip/hip_runtime.h>
#include <hip/hip_fp16.h>

typedef _Float16 half8 __attribute__((ext_vector_type(8)));
typedef float float4v __attribute__((ext_vector_type(4)));

#define CHUNK 2048           // edges per hist/scatter block
#define BCAP  6144           // LDS staging capacity in k_bucket

// ========== phase 1: per-chunk LDS histogram (1024 thr) + misc init in block 0 ==========
__global__ void __launch_bounds__(1024) k_hist(
        const int* __restrict__ dst, int E, int* __restrict__ histT, int K, int NBS,
        const float* __restrict__ W3, const float* __restrict__ fcW,
        const float* __restrict__ b3, float* __restrict__ wfc,
        double* __restrict__ pool, int* __restrict__ rowptr, int N) {
    __shared__ int lh[256];
    int t = threadIdx.x, b = blockIdx.x;
    if (t < 256) lh[t] = 0;
    __syncthreads();
    int base = b * CHUNK;
    #pragma unroll
    for (int i = 0; i < 2; ++i) {
        int e = base + i * 1024 + t;
        if (e < E) atomicAdd(&lh[dst[e] >> 8], 1);   // LDS atomic
    }
    __syncthreads();
    if (t < K) histT[t * NBS + b] = lh[t];
    if (b == 0) {                                    // fold tiny init work here
        if (t < 256) pool[t] = 0.0;
        if (t == 0) rowptr[N] = E;
        if (t < 64) {                                // wfc[c]=(W3@fcW)[c]; wfc[64]=b3.fcW
            float v = 0.f;
            #pragma unroll 8
            for (int j = 0; j < 64; ++j) v += W3[t * 64 + j] * fcW[j];
            wfc[t] = v;
            float bb = b3[t] * fcW[t];
            for (int o = 32; o > 0; o >>= 1) bb += __shfl_down(bb, o, 64);
            if (t == 0) wfc[64] = bb;
        }
    }
}

// ========== phase 2a: per-bucket totals (one wave per bucket) ==========
__global__ void k_tot(const int* __restrict__ histT, int NB, int NBS, int* __restrict__ tot) {
    int k = blockIdx.x, t = threadIdx.x;
    int s = 0;
    for (int b = t; b < NB; b += 64) s += histT[k * NBS + b];
    for (int o = 32; o > 0; o >>= 1) s += __shfl_down(s, o, 64);
    if (t == 0) tot[k] = s;
}

// ========== phase 2b: per-bucket chunk-offset scan; each block re-derives its base ==========
__global__ void k_offsets(int* __restrict__ histT, int NB, int NBS, int K,
                          const int* __restrict__ tot,
                          int* __restrict__ bucketBase, int* __restrict__ bucketCnt) {
    __shared__ int sc[256], tt[256];
    int k = blockIdx.x, t = threadIdx.x;
    int v = (t < K) ? tot[t] : 0;
    sc[t] = v; tt[t] = v;
    __syncthreads();
    for (int o = 1; o < 256; o <<= 1) {
        int u = (t >= o) ? sc[t - o] : 0;
        __syncthreads();
        sc[t] += u;
        __syncthreads();
    }
    int carry = sc[k] - tt[k];            // exclusive prefix at this block's bucket
    if (t == 0) { bucketBase[k] = carry; bucketCnt[k] = tt[k]; }
    for (int tile = 0; tile < NB; tile += 256) {
        int b = tile + t;
        int hv = (b < NB) ? histT[k * NBS + b] : 0;
        __syncthreads();
        sc[t] = hv;
        __syncthreads();
        for (int o = 1; o < 256; o <<= 1) {
            int u = (t >= o) ? sc[t - o] : 0;
            __syncthreads();
            sc[t] += u;
            __syncthreads();
        }
        if (b < NB) histT[k * NBS + b] = carry + sc[t] - hv;
        carry += sc[255];
    }
}

// ========== phase 3: scatter edges into bucket-partitioned pairs (1024 thr) ==========
__global__ void __launch_bounds__(1024) k_scatter(
        const int* __restrict__ src, const int* __restrict__ dst, int E,
        const int* __restrict__ histT, int K, int NBS, unsigned* __restrict__ pairs) {
    __shared__ int cur[256];
    int t = threadIdx.x, b = blockIdx.x;
    if (t < K) cur[t] = histT[t * NBS + b];
    __syncthreads();
    int base = b * CHUNK;
    #pragma unroll
    for (int i = 0; i < 2; ++i) {
        int e = base + i * 1024 + t;
        if (e < E) {
            int d = dst[e];
            int pos = atomicAdd(&cur[d >> 8], 1);    // LDS atomic
            pairs[pos] = ((unsigned)(d & 255) << 16) | (unsigned)src[e];
        }
    }
}

// ========== phase 4: per-bucket exact CSR + rowptr/dinv/gx (1024 thr) ==========
__global__ void __launch_bounds__(1024) k_bucket(
        const unsigned* __restrict__ pairs, const int* __restrict__ bucketBase,
        const int* __restrict__ bucketCnt, const float* __restrict__ x,
        int* __restrict__ rowptr, float* __restrict__ dinv,
        __half* __restrict__ gx, unsigned short* __restrict__ col, int N) {
    __shared__ unsigned pl[BCAP];
    __shared__ int h[256], nb[256], cur[256];
    int k = blockIdx.x, t = threadIdx.x;
    int base = bucketBase[k], cnt = bucketCnt[k];
    bool stg = cnt <= BCAP;
    if (t < 256) h[t] = 0;
    if (stg) for (int i = t; i < cnt; i += 1024) pl[i] = pairs[base + i];
    __syncthreads();
    for (int i = t; i < cnt; i += 1024) {
        unsigned p = stg ? pl[i] : pairs[base + i];
        atomicAdd(&h[p >> 16], 1);                   // LDS atomic
    }
    __syncthreads();
    int d = (t < 256) ? h[t] : 0;
    if (t < 256) nb[t] = d;
    __syncthreads();
    for (int o = 1; o < 256; o <<= 1) {
        int v = (t < 256 && t >= o) ? nb[t - o] : 0;
        __syncthreads();
        if (t < 256) nb[t] += v;
        __syncthreads();
    }
    if (t < 256) {
        int excl = nb[t] - d;
        cur[t] = excl;
        int gid = (k << 8) + t;
        if (gid < N) {
            rowptr[gid] = base + excl;
            float di = rsqrtf((float)(d + 1));       // +1 self loop
            dinv[gid] = di;
            #pragma unroll
            for (int q = 0; q < 16; ++q)
                gx[gid * 16 + q] = __float2half(q < 10 ? x[gid * 10 + q] * di : 0.f);
        }
    }
    __syncthreads();
    for (int i = t; i < cnt; i += 1024) {
        unsigned p = stg ? pl[i] : pairs[base + i];
        int j = p >> 16;
        int pos = atomicAdd(&cur[j], 1);             // LDS atomic
        col[base + pos] = (unsigned short)(p & 0xFFFFu);
    }
}

// ========== layer 1: gather gx16 (1.6MB, L2-resident), 16 lanes/node ==========
__global__ void k_L1(const __half* __restrict__ gx, const float* __restrict__ W1,
                     const float* __restrict__ b1, const int* __restrict__ rowptr,
                     const unsigned short* __restrict__ col, const float* __restrict__ dinv,
                     __half* __restrict__ g1a, __half* __restrict__ g1b, int N) {
    __shared__ float sW[10 * 64];
    __shared__ float sB[64];
    int t = threadIdx.x;
    for (int i = t; i < 640; i += 256) sW[i] = W1[i];
    if (t < 64) sB[t] = b1[t];
    __syncthreads();
    int node = blockIdx.x * 16 + (t >> 4);
    int f = t & 15;
    bool live = node < N;
    bool act = live && (f < 10);
    const char* gp = (const char*)gx;
    unsigned fo = (unsigned)(f << 1);
    float di = live ? dinv[node] : 0.f;
    float a = act ? __half2float(*(const __half*)(gp + ((unsigned)node << 5) + fo)) : 0.f;
    int s0 = 0, s1 = 0;
    if (live) { s0 = rowptr[node]; s1 = rowptr[node + 1]; }
    int e = s0;
    for (; e + 4 <= s1; e += 4) {
        unsigned j0 = col[e], j1 = col[e + 1], j2 = col[e + 2], j3 = col[e + 3];
        float v0 = 0.f, v1 = 0.f, v2 = 0.f, v3 = 0.f;
        if (act) {
            v0 = __half2float(*(const __half*)(gp + (j0 << 5) + fo));
            v1 = __half2float(*(const __half*)(gp + (j1 << 5) + fo));
            v2 = __half2float(*(const __half*)(gp + (j2 << 5) + fo));
            v3 = __half2float(*(const __half*)(gp + (j3 << 5) + fo));
        }
        a += (v0 + v1) + (v2 + v3);
    }
    for (; e < s1; ++e) {
        unsigned j = col[e];
        if (act) a += __half2float(*(const __half*)(gp + (j << 5) + fo));
    }
    a *= di;                                   // P_i(x)[f], f<10
    int gb = t & 48;
    float c0 = 0.f, c1 = 0.f, c2 = 0.f, c3 = 0.f;
    int c4 = 4 * f;
    #pragma unroll
    for (int k = 0; k < 10; ++k) {
        float ak = __shfl(a, gb + k, 64);
        c0 += ak * sW[k * 64 + c4];
        c1 += ak * sW[k * 64 + c4 + 1];
        c2 += ak * sW[k * 64 + c4 + 2];
        c3 += ak * sW[k * 64 + c4 + 3];
    }
    if (!live) return;
    float h0 = di * fmaxf(c0 + sB[c4], 0.f);
    float h1 = di * fmaxf(c1 + sB[c4 + 1], 0.f);
    float h2 = di * fmaxf(c2 + sB[c4 + 2], 0.f);
    float h3 = di * fmaxf(c3 + sB[c4 + 3], 0.f);
    union { __half h[4]; uint2 u; } pk;
    pk.h[0] = __float2half(h0); pk.h[1] = __float2half(h1);
    pk.h[2] = __float2half(h2); pk.h[3] = __float2half(h3);
    if (f < 8)
        *(uint2*)((char*)g1a + ((unsigned)node << 6) + (unsigned)(f << 3)) = pk.u;
    else
        *(uint2*)((char*)g1b + ((unsigned)node << 6) + (unsigned)((f - 8) << 3)) = pk.u;
}

// ========== layer 2 pass A: gather g1a (3.2MB, L2-resident) -> a2a fp16 ==========
__global__ void __launch_bounds__(256) k_L2a(
        const __half* __restrict__ g1a, const int* __restrict__ rowptr,
        const unsigned short* __restrict__ col, const float* __restrict__ dinv,
        __half* __restrict__ a2a, int N) {
    int t = threadIdx.x;
    int node = blockIdx.x * 16 + (t >> 4);
    int f4 = t & 15;
    if (node >= N) return;
    float di = dinv[node];
    const char* gp = (const char*)g1a;
    unsigned fo = (unsigned)(f4 << 2);
    unsigned u = *(const unsigned*)(gp + ((unsigned)node << 6) + fo);
    float2 a = __half22float2(*(__half2*)&u);
    int s0 = rowptr[node], s1 = rowptr[node + 1];
    int e = s0;
    for (; e + 8 <= s1; e += 8) {
        unsigned j0 = col[e],     j1 = col[e + 1], j2 = col[e + 2], j3 = col[e + 3];
        unsigned j4 = col[e + 4], j5 = col[e + 5], j6 = col[e + 6], j7 = col[e + 7];
        unsigned u0 = *(const unsigned*)(gp + (j0 << 6) + fo);
        unsigned u1 = *(const unsigned*)(gp + (j1 << 6) + fo);
        unsigned u2 = *(const unsigned*)(gp + (j2 << 6) + fo);
        unsigned u3 = *(const unsigned*)(gp + (j3 << 6) + fo);
        unsigned u4 = *(const unsigned*)(gp + (j4 << 6) + fo);
        unsigned u5 = *(const unsigned*)(gp + (j5 << 6) + fo);
        unsigned u6 = *(const unsigned*)(gp + (j6 << 6) + fo);
        unsigned u7 = *(const unsigned*)(gp + (j7 << 6) + fo);
        float2 f0 = __half22float2(*(__half2*)&u0), f1 = __half22float2(*(__half2*)&u1);
        float2 f2 = __half22float2(*(__half2*)&u2), f3 = __half22float2(*(__half2*)&u3);
        float2 f4v = __half22float2(*(__half2*)&u4), f5 = __half22float2(*(__half2*)&u5);
        float2 f6 = __half22float2(*(__half2*)&u6), f7 = __half22float2(*(__half2*)&u7);
        a.x += ((f0.x + f1.x) + (f2.x + f3.x)) + ((f4v.x + f5.x) + (f6.x + f7.x));
        a.y += ((f0.y + f1.y) + (f2.y + f3.y)) + ((f4v.y + f5.y) + (f6.y + f7.y));
    }
    for (; e < s1; ++e) {
        unsigned u1 = *(const unsigned*)(gp + ((unsigned)col[e] << 6) + fo);
        float2 f1 = __half22float2(*(__half2*)&u1);
        a.x += f1.x; a.y += f1.y;
    }
    __half2 hv = __floats2half2_rn(a.x * di, a.y * di);
    __builtin_nontemporal_store(*(unsigned*)&hv,
        (unsigned*)((char*)a2a + ((unsigned)node << 6) + fo));
}

// ========== layer 2 pass B: gather g1b + merge a2a + MFMA epilogue -> tvec ==========
__global__ void __launch_bounds__(256) k_L2b(
        const __half* __restrict__ g1b, const __half* __restrict__ a2a,
        const float* __restrict__ W2, const float* __restrict__ b2,
        const float* __restrict__ wfcv, const int* __restrict__ rowptr,
        const unsigned short* __restrict__ col, const float* __restrict__ dinv,
        float* __restrict__ tvec, int N) {
    __shared__ __half At[16 * 72];     // 16 nodes x 64 feats, stride 72
    __shared__ float sRed[4][16];
    __shared__ float sDi[16];
    int t = threadIdx.x;
    int lane = t & 63, wid = t >> 6;
    int m = lane & 15, quad = lane >> 4;

    // B fragments: W2 column cg, fp16 hi/lo split (registers, overlaps gather)
    int cg = (wid << 4) + m;
    half8 H0, L0, H1, L1;
    #pragma unroll
    for (int j = 0; j < 8; ++j) {
        float w0 = W2[(quad * 8 + j) * 64 + cg];
        _Float16 h0 = (_Float16)w0;
        H0[j] = h0; L0[j] = (_Float16)(w0 - (float)h0);
        float w1 = W2[(32 + quad * 8 + j) * 64 + cg];
        _Float16 h1 = (_Float16)w1;
        H1[j] = h1; L1[j] = (_Float16)(w1 - (float)h1);
    }
    float bc = b2[cg], wf = wfcv[cg];

    // gather g1b: 16 nodes/block, 16 lanes/node, 2 feats (uint) per lane
    int nl = t >> 4, f4 = t & 15;
    int node = blockIdx.x * 16 + nl;
    bool live = node < N;
    float di = live ? dinv[node] : 0.f;
    float ax = 0.f, ay = 0.f;
    unsigned ua = 0u;
    if (live) {
        const char* gp = (const char*)g1b;
        unsigned fo = (unsigned)(f4 << 2);
        unsigned u = *(const unsigned*)(gp + ((unsigned)node << 6) + fo);
        float2 fs = __half22float2(*(__half2*)&u);
        ax = fs.x; ay = fs.y;
        int s0 = rowptr[node], s1 = rowptr[node + 1];
        int e = s0;
        for (; e + 8 <= s1; e += 8) {
            unsigned j0 = col[e],     j1 = col[e + 1], j2 = col[e + 2], j3 = col[e + 3];
            unsigned j4 = col[e + 4], j5 = col[e + 5], j6 = col[e + 6], j7 = col[e + 7];
            unsigned u0 = *(const unsigned*)(gp + (j0 << 6) + fo);
            unsigned u1 = *(const unsigned*)(gp + (j1 << 6) + fo);
            unsigned u2 = *(const unsigned*)(gp + (j2 << 6) + fo);
            unsigned u3 = *(const unsigned*)(gp + (j3 << 6) + fo);
            unsigned u4 = *(const unsigned*)(gp + (j4 << 6) + fo);
            unsigned u5 = *(const unsigned*)(gp + (j5 << 6) + fo);
            unsigned u6 = *(const unsigned*)(gp + (j6 << 6) + fo);
            unsigned u7 = *(const unsigned*)(gp + (j7 << 6) + fo);
            float2 f0 = __half22float2(*(__half2*)&u0), f1 = __half22float2(*(__half2*)&u1);
            float2 f2 = __half22float2(*(__half2*)&u2), f3 = __half22float2(*(__half2*)&u3);
            float2 f4v = __half22float2(*(__half2*)&u4), f5 = __half22float2(*(__half2*)&u5);
            float2 f6 = __half22float2(*(__half2*)&u6), f7 = __half22float2(*(__half2*)&u7);
            ax += ((f0.x + f1.x) + (f2.x + f3.x)) + ((f4v.x + f5.x) + (f6.x + f7.x));
            ay += ((f0.y + f1.y) + (f2.y + f3.y)) + ((f4v.y + f5.y) + (f6.y + f7.y));
        }
        for (; e < s1; ++e) {
            unsigned u1 = *(const unsigned*)(gp + ((unsigned)col[e] << 6) + fo);
            float2 f1 = __half22float2(*(__half2*)&u1);
            ax += f1.x; ay += f1.y;
        }
        ua = __builtin_nontemporal_load(
            (const unsigned*)((const char*)a2a + ((unsigned)node << 6) + fo));
    }
    __half2 hv = __floats2half2_rn(ax * di, ay * di);
    *(unsigned*)&At[nl * 72 + 32 + 2 * f4] = *(unsigned*)&hv;   // b-half
    *(unsigned*)&At[nl * 72 + 2 * f4] = ua;                     // a-half (from pass A)
    if (f4 == 0) sDi[nl] = di;
    __syncthreads();

    // MFMA: D[m=node][n=col] = A(16x64) @ W2(64x64); this wave: cols 16*wid..
    half8 A0 = *reinterpret_cast<const half8*>(&At[m * 72 + quad * 8]);
    half8 A1 = *reinterpret_cast<const half8*>(&At[m * 72 + 32 + quad * 8]);
    float4v C = {0.f, 0.f, 0.f, 0.f};
    C = __builtin_amdgcn_mfma_f32_16x16x32_f16(A0, H0, C, 0, 0, 0);
    C = __builtin_amdgcn_mfma_f32_16x16x32_f16(A0, L0, C, 0, 0, 0);
    C = __builtin_amdgcn_mfma_f32_16x16x32_f16(A1, H1, C, 0, 0, 0);
    C = __builtin_amdgcn_mfma_f32_16x16x32_f16(A1, L1, C, 0, 0, 0);

    // epilogue: relu(C+b2)*wfc, reduce over cols -> per-node scalar
    float v0 = fmaxf(C[0] + bc, 0.f) * wf;
    float v1 = fmaxf(C[1] + bc, 0.f) * wf;
    float v2 = fmaxf(C[2] + bc, 0.f) * wf;
    float v3 = fmaxf(C[3] + bc, 0.f) * wf;
    #pragma unroll
    for (int o = 1; o < 16; o <<= 1) {
        v0 += __shfl_xor(v0, o, 64);
        v1 += __shfl_xor(v1, o, 64);
        v2 += __shfl_xor(v2, o, 64);
        v3 += __shfl_xor(v3, o, 64);
    }
    if (m == 0) {
        sRed[wid][quad * 4 + 0] = v0;
        sRed[wid][quad * 4 + 1] = v1;
        sRed[wid][quad * 4 + 2] = v2;
        sRed[wid][quad * 4 + 3] = v3;
    }
    __syncthreads();
    if (t < 16) {
        int ng = blockIdx.x * 16 + t;
        if (ng < N) {
            float tt = sRed[0][t] + sRed[1][t] + sRed[2][t] + sRed[3][t];
            tvec[ng] = sDi[t] * tt;            // t_j = dinv_j * (h2_j . wfc)
        }
    }
}

// ========== layer 3: scalar gather over tvec (200KB) + mean-pool ==========
__global__ void k_agg3(const float* __restrict__ tvec, const int* __restrict__ rowptr,
                       const unsigned short* __restrict__ col, const float* __restrict__ dinv,
                       double* __restrict__ pool, int N) {
    int tid = blockIdx.x * 256 + threadIdx.x;
    int node = tid >> 4, lane = tid & 15;
    if (node >= N) return;
    int s0 = rowptr[node], s1 = rowptr[node + 1];
    float s = 0.f;
    for (int e = s0 + lane; e < s1; e += 16) s += tvec[col[e]];
    #pragma unroll
    for (int o = 1; o < 16; o <<= 1) s += __shfl_xor(s, o, 64);
    if (lane == 0) {
        double contrib = (double)(dinv[node] * (tvec[node] + s));
        atomicAdd(&pool[node & 255], contrib);
    }
}

__global__ void k_final(const double* __restrict__ pool, const float* __restrict__ wfc,
                        const float* __restrict__ fcb, float* __restrict__ out, double invN) {
    __shared__ double s[256];
    int t = threadIdx.x;
    s[t] = pool[t];
    __syncthreads();
    for (int o = 128; o > 0; o >>= 1) {
        if (t < o) s[t] += s[t + o];
        __syncthreads();
    }
    if (t == 0) out[0] = (float)(s[0] * invN) + wfc[64] + fcb[0];
}

extern "C" void kernel_launch(void* const* d_in, const int* in_sizes, int n_in,
                              void* d_out, int out_size, void* d_ws, size_t ws_size,
                              hipStream_t stream) {
    const float* x   = (const float*)d_in[0];
    const int*   ei  = (const int*)d_in[1];
    const float* W1  = (const float*)d_in[2];
    const float* b1  = (const float*)d_in[3];
    const float* W2  = (const float*)d_in[4];
    const float* b2  = (const float*)d_in[5];
    const float* W3  = (const float*)d_in[6];
    const float* b3  = (const float*)d_in[7];
    const float* fcW = (const float*)d_in[8];
    const float* fcb = (const float*)d_in[9];

    const int N = in_sizes[0] / 10;
    const int E = in_sizes[1] / 2;
    const int* src = ei;
    const int* dst = ei + E;

    const int K   = (N + 255) >> 8;            // buckets of 256 nodes (196)
    const int NB  = (E + CHUNK - 1) / CHUNK;   // chunks (391)
    const int NBS = NB | 1;                    // odd stride

    // ---- workspace carve-up (256B aligned) ----
    char* w = (char*)d_ws;
    size_t off = 0;
    auto alloc = [&](size_t bytes) -> void* {
        void* p = w + off;
        off += (bytes + 255) & ~(size_t)255;
        return p;
    };
    int*      histT      = (int*)alloc((size_t)K * NBS * 4);
    int*      tot        = (int*)alloc((size_t)K * 4);
    int*      bucketBase = (int*)alloc((size_t)K * 4);
    int*      bucketCnt  = (int*)alloc((size_t)K * 4);
    unsigned* pairs      = (unsigned*)alloc((size_t)E * 4);
    unsigned short* col  = (unsigned short*)alloc((size_t)E * 2);
    int*      rowptr     = (int*)alloc((size_t)(N + 1) * 4);
    float*    dinv       = (float*)alloc((size_t)N * 4);
    double*   pool       = (double*)alloc(256 * 8);
    float*    wfc        = (float*)alloc(65 * 4);
    float*    tvec       = (float*)alloc((size_t)N * 4);
    __half*   gx         = (__half*)alloc((size_t)N * 16 * 2);
    __half*   g1a        = (__half*)alloc((size_t)N * 32 * 2);
    __half*   g1b        = (__half*)alloc((size_t)N * 32 * 2);
    __half*   a2a        = (__half*)alloc((size_t)N * 32 * 2);
    (void)ws_size; (void)n_in; (void)out_size;

    const int nbNode16 = (N + 15) / 16;

    // ---- atomic-free CSR build (counting sort, LDS atomics only) ----
    k_hist   <<<NB, 1024, 0, stream>>>(dst, E, histT, K, NBS,
                                       W3, fcW, b3, wfc, pool, rowptr, N);
    k_tot    <<<K, 64, 0, stream>>>(histT, NB, NBS, tot);
    k_offsets<<<K, 256, 0, stream>>>(histT, NB, NBS, K, tot, bucketBase, bucketCnt);
    k_scatter<<<NB, 1024, 0, stream>>>(src, dst, E, histT, K, NBS, pairs);
    k_bucket <<<K, 1024, 0, stream>>>(pairs, bucketBase, bucketCnt, x,
                                      rowptr, dinv, gx, col, N);

    // ---- fused layers ----
    k_L1 <<<nbNode16, 256, 0, stream>>>(gx, W1, b1, rowptr, col, dinv, g1a, g1b, N);
    k_L2a<<<nbNode16, 256, 0, stream>>>(g1a, rowptr, col, dinv, a2a, N);
    k_L2b<<<nbNode16, 256, 0, stream>>>(g1b, a2a, W2, b2, wfc, rowptr, col, dinv, tvec, N);
    k_agg3<<<nbNode16, 256, 0, stream>>>(tvec, rowptr, col, dinv, pool, N);
    k_final<<<1, 256, 0, stream>>>(pool, wfc, fcb, (float*)d_out, 1.0 / (double)N);
}